// Round 4
// baseline (580.542 us; speedup 1.0000x reference)
//
#include <hip/hip_runtime.h>
#include <hip/hip_bf16.h>

// Problem constants (fixed by the reference)
#define NN 50000      // nodes
#define EE 800000     // raw edges
#define TE 850000     // edges + self loops
#define NCH 196       // ceil(NN/256) chunks for the scan

typedef __hip_bfloat16 bf16;

__device__ __forceinline__ float b2f(__hip_bfloat16 v) { return __bfloat162float(v); }

// ---------------- runtime edge-index width detection ----------------
// flags[0] = 1 if edge_index is int64 (else int32)
__global__ void detect_k(const unsigned int* __restrict__ eir, int* __restrict__ flags) {
    __shared__ int ci;
    int t = threadIdx.x;
    if (t == 0) ci = 0;
    __syncthreads();
    if (t < 64 && eir[2 * t + 1] == 0) atomicAdd(&ci, 1);
    __syncthreads();
    if (t == 0) flags[0] = (ci >= 32) ? 1 : 0;  // int64 -> 64 zero high-words
}

__device__ __forceinline__ int load_edge(const void* ei, int isi64, long long idx) {
    int v = isi64 ? (int)((const long long*)ei)[idx] : ((const int*)ei)[idx];
    return (v < 0) ? 0 : (v >= NN ? NN - 1 : v);  // clamp: belt & braces
}

// ---------------- CSR build (by dst) ----------------

__global__ void count_deg_k(const void* __restrict__ ei, const int* __restrict__ flags,
                            int* __restrict__ deg) {
    int i = blockIdx.x * 256 + threadIdx.x;
    if (i >= TE) return;
    int d = (i < EE) ? load_edge(ei, flags[0], (long long)EE + i) : (i - EE);
    atomicAdd(&deg[d], 1);
}

// single block: chunk sums + exclusive scan of 196 chunk sums
__global__ void scan_chunks_k(const int* __restrict__ deg, int* __restrict__ chunkoff) {
    __shared__ int s[256];
    int t = threadIdx.x;
    int sum = 0;
    if (t < NCH) {
        int base = t * 256;
        for (int j = 0; j < 256; ++j) {
            int idx = base + j;
            if (idx < NN) sum += deg[idx];
        }
    }
    s[t] = sum;
    __syncthreads();
    for (int d = 1; d < 256; d <<= 1) {
        int v = (t >= d) ? s[t - d] : 0;
        __syncthreads();
        s[t] += v;
        __syncthreads();
    }
    if (t < NCH) chunkoff[t] = s[t] - sum;   // exclusive
}

// per-chunk scan -> global exclusive offsets; offs has NN+1 entries
__global__ void scan_within_k(const int* __restrict__ deg, const int* __restrict__ chunkoff,
                              int* __restrict__ offs) {
    __shared__ int s[256];
    int t = threadIdx.x, b = blockIdx.x, i = b * 256 + t;
    int v = (i < NN) ? deg[i] : 0;
    s[t] = v;
    __syncthreads();
    for (int d = 1; d < 256; d <<= 1) {
        int u = (t >= d) ? s[t - d] : 0;
        __syncthreads();
        s[t] += u;
        __syncthreads();
    }
    if (i < NN) offs[i] = chunkoff[b] + s[t] - v;
    if (i == NN - 1) offs[NN] = chunkoff[b] + s[t];
}

__global__ void fill_csr_k(const void* __restrict__ ei, const int* __restrict__ flags,
                           const int* __restrict__ offs,
                           int* __restrict__ cursor, int* __restrict__ csr_src) {
    int i = blockIdx.x * 256 + threadIdx.x;
    if (i >= TE) return;
    int sdx, d;
    if (i < EE) {
        int isi64 = flags[0];
        sdx = load_edge(ei, isi64, i);
        d   = load_edge(ei, isi64, (long long)EE + i);
    } else {
        sdx = i - EE; d = i - EE;
    }
    int pos = offs[d] + atomicAdd(&cursor[d], 1);
    csr_src[pos] = sdx;
}

// ---------------- Layer 1: h1 = x@W1, alpha_src/dst per head ----------------
// block = 256 threads (tid = output col = head*16+ch), 8 rows per block
__global__ void gemm1_k(const float* __restrict__ xf, const float* __restrict__ W1,
                        const float* __restrict__ asr, const float* __restrict__ ads,
                        bf16* __restrict__ h1,
                        float* __restrict__ a_src, float* __restrict__ a_dst) {
    __shared__ float xs[8 * 128];
    int tid = threadIdx.x;
    int base = blockIdx.x * 8;
    for (int i = tid; i < 8 * 128; i += 256) xs[i] = xf[base * 128 + i];
    __syncthreads();
    float acc[8];
#pragma unroll
    for (int r = 0; r < 8; ++r) acc[r] = 0.f;
    for (int k = 0; k < 128; ++k) {
        float w = W1[k * 256 + tid];
#pragma unroll
        for (int r = 0; r < 8; ++r) acc[r] += xs[r * 128 + k] * w;
    }
    float av = asr[tid], bv = ads[tid];
#pragma unroll
    for (int r = 0; r < 8; ++r) {
        h1[(base + r) * 256 + tid] = __float2bfloat16(acc[r]);
        float ps = acc[r] * av, pd = acc[r] * bv;
#pragma unroll
        for (int o = 8; o >= 1; o >>= 1) {
            ps += __shfl_xor(ps, o, 64);
            pd += __shfl_xor(pd, o, 64);
        }
        if ((tid & 15) == 0) {
            a_src[(base + r) * 16 + (tid >> 4)] = ps;
            a_dst[(base + r) * 16 + (tid >> 4)] = pd;
        }
    }
}

// ---------------- Layer 1 aggregation: online softmax over incoming edges ----
// block = 256 threads = one dst node; tid = head*16 + ch
__global__ void agg1_k(const int* __restrict__ offs, const int* __restrict__ csr_src,
                       const float* __restrict__ a_src, const float* __restrict__ a_dst,
                       const bf16* __restrict__ h1, const float* __restrict__ b1,
                       bf16* __restrict__ out1) {
    int dst = blockIdx.x;
    int tid = threadIdx.x;
    int h = tid >> 4;
    int start = offs[dst], end = offs[dst + 1];
    float adst = a_dst[dst * 16 + h];
    __shared__ int sidx[256];
    float m = -INFINITY, l = 0.f, acc = 0.f;
    for (int t0 = start; t0 < end; t0 += 256) {
        int n = end - t0; if (n > 256) n = 256;
        if (tid < n) sidx[tid] = csr_src[t0 + tid];
        __syncthreads();
        for (int j = 0; j < n; ++j) {
            int s = sidx[j];
            float e = a_src[s * 16 + h] + adst;
            e = (e > 0.f) ? e : 0.2f * e;          // LeakyReLU(0.2)
            float nm = fmaxf(m, e);
            float sc = __expf(m - nm);
            float p  = __expf(e - nm);
            float hv = b2f(h1[s * 256 + tid]);
            acc = acc * sc + p * hv;
            l   = l * sc + p;
            m   = nm;
        }
        __syncthreads();
    }
    out1[dst * 256 + tid] = __float2bfloat16(acc / (l + 1e-16f) + b1[tid]);
}

// ---------------- Layer 2: h2 = out1@W2, alpha2 (1 head, 64 ch) -------------
// block = 256 threads = 4 rows x 64 cols (one wave per row)
__global__ void gemm2_k(const bf16* __restrict__ out1, const float* __restrict__ W2,
                        const float* __restrict__ asr2, const float* __restrict__ ads2,
                        float* __restrict__ h2,
                        float* __restrict__ a_src2, float* __restrict__ a_dst2) {
    __shared__ float ys[4 * 256];
    int tid = threadIdx.x;
    int r = tid >> 6, c = tid & 63;
    int base = blockIdx.x * 4;
    for (int i = tid; i < 4 * 256; i += 256) ys[i] = b2f(out1[base * 256 + i]);
    __syncthreads();
    float acc = 0.f;
    for (int k = 0; k < 256; ++k) acc += ys[r * 256 + k] * W2[k * 64 + c];
    h2[(base + r) * 64 + c] = acc;
    float ps = acc * asr2[c];
    float pd = acc * ads2[c];
#pragma unroll
    for (int o = 32; o >= 1; o >>= 1) {
        ps += __shfl_xor(ps, o, 64);
        pd += __shfl_xor(pd, o, 64);
    }
    if (c == 0) { a_src2[base + r] = ps; a_dst2[base + r] = pd; }
}

// ---------------- Layer 2 aggregation + sigmoid -----------------------------
// block = 256 threads = 4 dst nodes (one wave each); lane = channel (64)
// OUTPUT IS FLOAT32 (reference output dtype)
__global__ void agg2_k(const int* __restrict__ offs, const int* __restrict__ csr_src,
                       const float* __restrict__ a_src2, const float* __restrict__ a_dst2,
                       const float* __restrict__ h2, const float* __restrict__ b2,
                       float* __restrict__ out) {
    int w = threadIdx.x >> 6;
    int c = threadIdx.x & 63;
    int dst = blockIdx.x * 4 + w;
    if (dst >= NN) return;
    int start = offs[dst], end = offs[dst + 1];
    float adst = a_dst2[dst];
    float m = -INFINITY, l = 0.f, acc = 0.f;
    for (int j = start; j < end; ++j) {
        int s = csr_src[j];
        float e = a_src2[s] + adst;
        e = (e > 0.f) ? e : 0.2f * e;
        float nm = fmaxf(m, e);
        float sc = __expf(m - nm);
        float p  = __expf(e - nm);
        float hv = h2[s * 64 + c];
        acc = acc * sc + p * hv;
        l   = l * sc + p;
        m   = nm;
    }
    float o = acc / (l + 1e-16f) + b2[c];
    out[dst * 64 + c] = 1.f / (1.f + __expf(-o));
}

// ---------------- host ------------------------------------------------------

extern "C" void kernel_launch(void* const* d_in, const int* in_sizes, int n_in,
                              void* d_out, int out_size, void* d_ws, size_t ws_size,
                              hipStream_t stream) {
    const float* x    = (const float*)d_in[0];
    const void*  ei   = d_in[1];
    const float* W1   = (const float*)d_in[2];
    const float* asr1 = (const float*)d_in[3];
    const float* ads1 = (const float*)d_in[4];
    const float* b1   = (const float*)d_in[5];
    const float* W2   = (const float*)d_in[6];
    const float* asr2 = (const float*)d_in[7];
    const float* ads2 = (const float*)d_in[8];
    const float* b2   = (const float*)d_in[9];
    float* out = (float*)d_out;   // f32 output (reference output dtype)

    // workspace carve (256B aligned)
    char* w = (char*)d_ws;
    auto carve = [&](size_t bytes) {
        void* p = (void*)w;
        w += (bytes + 255) & ~(size_t)255;
        return p;
    };
    int*   flags    = (int*)carve(256);
    int*   csr_src  = (int*)carve((size_t)TE * 4);            // 3.4 MB
    int*   offs     = (int*)carve((size_t)(NN + 1) * 4);
    int*   deg      = (int*)carve((size_t)NN * 4);
    int*   cursor   = (int*)carve((size_t)NN * 4);
    int*   chunkoff = (int*)carve(256 * 4);
    float* a_src1   = (float*)carve((size_t)NN * 16 * 4);     // 3.2 MB
    float* a_dst1   = (float*)carve((size_t)NN * 16 * 4);     // 3.2 MB
    bf16*  h1       = (bf16*)carve((size_t)NN * 256 * 2);     // 25.6 MB
    bf16*  out1     = (bf16*)carve((size_t)NN * 256 * 2);     // 25.6 MB
    // aliases (disjoint lifetimes):
    float* h2       = (float*)h1;   // 12.8 MB over h1's 25.6 (h1 dead after agg1)
    float* a_src2   = a_src1;       // dead after agg1
    float* a_dst2   = a_dst1;
    // peak footprint ~62 MB

    hipMemsetAsync(deg, 0, (size_t)NN * 4, stream);
    hipMemsetAsync(cursor, 0, (size_t)NN * 4, stream);

    detect_k<<<1, 256, 0, stream>>>((const unsigned int*)ei, flags);

    const int egrid = (TE + 255) / 256;
    count_deg_k<<<egrid, 256, 0, stream>>>(ei, flags, deg);
    scan_chunks_k<<<1, 256, 0, stream>>>(deg, chunkoff);
    scan_within_k<<<NCH, 256, 0, stream>>>(deg, chunkoff, offs);
    fill_csr_k<<<egrid, 256, 0, stream>>>(ei, flags, offs, cursor, csr_src);

    gemm1_k<<<NN / 8, 256, 0, stream>>>(x, W1, asr1, ads1, h1, a_src1, a_dst1);
    agg1_k<<<NN, 256, 0, stream>>>(offs, csr_src, a_src1, a_dst1, h1, b1, out1);
    gemm2_k<<<NN / 4, 256, 0, stream>>>(out1, W2, asr2, ads2, h2, a_src2, a_dst2);
    agg2_k<<<(NN + 3) / 4, 256, 0, stream>>>(offs, csr_src, a_src2, a_dst2, h2, b2, out);
}

// Round 5
// 494.194 us; speedup vs baseline: 1.1747x; 1.1747x over previous
//
#include <hip/hip_runtime.h>
#include <hip/hip_bf16.h>

// Problem constants (fixed by the reference)
#define NN 50000      // nodes
#define EE 800000     // raw edges
#define TE 850000     // edges + self loops
#define NCH 196       // ceil(NN/256) chunks for the scan

typedef __hip_bfloat16 bf16;

__device__ __forceinline__ float b2f(bf16 v) { return __bfloat162float(v); }
__device__ __forceinline__ unsigned short f2bu(float v) {
    bf16 t = __float2bfloat16(v);
    return *(unsigned short*)&t;
}

// ---------------- runtime edge-index width detection ----------------
// flags[0] = 1 if edge_index is int64 (else int32)
__global__ void detect_k(const unsigned int* __restrict__ eir, int* __restrict__ flags) {
    __shared__ int ci;
    int t = threadIdx.x;
    if (t == 0) ci = 0;
    __syncthreads();
    if (t < 64 && eir[2 * t + 1] == 0) atomicAdd(&ci, 1);
    __syncthreads();
    if (t == 0) flags[0] = (ci >= 32) ? 1 : 0;
}

__device__ __forceinline__ int load_edge(const void* ei, int isi64, long long idx) {
    int v = isi64 ? (int)((const long long*)ei)[idx] : ((const int*)ei)[idx];
    return (v < 0) ? 0 : (v >= NN ? NN - 1 : v);
}

// ---------------- CSR build (by dst) ----------------

__global__ void count_deg_k(const void* __restrict__ ei, const int* __restrict__ flags,
                            int* __restrict__ deg) {
    int i = blockIdx.x * 256 + threadIdx.x;
    if (i >= TE) return;
    int d = (i < EE) ? load_edge(ei, flags[0], (long long)EE + i) : (i - EE);
    atomicAdd(&deg[d], 1);
}

__global__ void scan_chunks_k(const int* __restrict__ deg, int* __restrict__ chunkoff) {
    __shared__ int s[256];
    int t = threadIdx.x;
    int sum = 0;
    if (t < NCH) {
        int base = t * 256;
        for (int j = 0; j < 256; ++j) {
            int idx = base + j;
            if (idx < NN) sum += deg[idx];
        }
    }
    s[t] = sum;
    __syncthreads();
    for (int d = 1; d < 256; d <<= 1) {
        int v = (t >= d) ? s[t - d] : 0;
        __syncthreads();
        s[t] += v;
        __syncthreads();
    }
    if (t < NCH) chunkoff[t] = s[t] - sum;
}

__global__ void scan_within_k(const int* __restrict__ deg, const int* __restrict__ chunkoff,
                              int* __restrict__ offs) {
    __shared__ int s[256];
    int t = threadIdx.x, b = blockIdx.x, i = b * 256 + t;
    int v = (i < NN) ? deg[i] : 0;
    s[t] = v;
    __syncthreads();
    for (int d = 1; d < 256; d <<= 1) {
        int u = (t >= d) ? s[t - d] : 0;
        __syncthreads();
        s[t] += u;
        __syncthreads();
    }
    if (i < NN) offs[i] = chunkoff[b] + s[t] - v;
    if (i == NN - 1) offs[NN] = chunkoff[b] + s[t];
}

__global__ void fill_csr_k(const void* __restrict__ ei, const int* __restrict__ flags,
                           const int* __restrict__ offs,
                           int* __restrict__ cursor, int* __restrict__ csr_src) {
    int i = blockIdx.x * 256 + threadIdx.x;
    if (i >= TE) return;
    int sdx, d;
    if (i < EE) {
        int isi64 = flags[0];
        sdx = load_edge(ei, isi64, i);
        d   = load_edge(ei, isi64, (long long)EE + i);
    } else {
        sdx = i - EE; d = i - EE;
    }
    int pos = offs[d] + atomicAdd(&cursor[d], 1);
    csr_src[pos] = sdx;
}

// ---------------- Layer 1 GEMM: h1 = x@W1 (bf16 out) + alpha partials -------
// block 256 = 32 rows x 256 cols; thread = 4 cols (cg*4) x 8 rows (rg*8..+7)
__global__ __launch_bounds__(256) void gemm1_k(
    const float* __restrict__ x, const float* __restrict__ W1,
    const float* __restrict__ asr, const float* __restrict__ ads,
    bf16* __restrict__ h1, float* __restrict__ a_src, float* __restrict__ a_dst) {
    __shared__ float4 xs4[32 * 32];   // [row][kq] 32 rows x 128 k as float4
    int tid = threadIdx.x;
    int base = blockIdx.x * 32;
    const float4* x4 = (const float4*)x;
    for (int i = tid; i < 1024; i += 256) {
        int row = base + (i >> 5);
        xs4[i] = (row < NN) ? x4[(size_t)base * 32 + i] : make_float4(0.f, 0.f, 0.f, 0.f);
    }
    __syncthreads();
    int cg = tid & 63, rg = tid >> 6;
    int c0 = cg * 4;
    float4 acc[8];
#pragma unroll
    for (int r = 0; r < 8; ++r) acc[r] = make_float4(0.f, 0.f, 0.f, 0.f);
    for (int kq = 0; kq < 32; ++kq) {
        float4 w0 = *(const float4*)&W1[(kq * 4 + 0) * 256 + c0];
        float4 w1 = *(const float4*)&W1[(kq * 4 + 1) * 256 + c0];
        float4 w2 = *(const float4*)&W1[(kq * 4 + 2) * 256 + c0];
        float4 w3 = *(const float4*)&W1[(kq * 4 + 3) * 256 + c0];
#pragma unroll
        for (int r = 0; r < 8; ++r) {
            float4 xv = xs4[(rg * 8 + r) * 32 + kq];
            acc[r].x += xv.x * w0.x + xv.y * w1.x + xv.z * w2.x + xv.w * w3.x;
            acc[r].y += xv.x * w0.y + xv.y * w1.y + xv.z * w2.y + xv.w * w3.y;
            acc[r].z += xv.x * w0.z + xv.y * w1.z + xv.z * w2.z + xv.w * w3.z;
            acc[r].w += xv.x * w0.w + xv.y * w1.w + xv.z * w2.w + xv.w * w3.w;
        }
    }
    int h = cg >> 2;
    float sa0 = asr[c0], sa1 = asr[c0 + 1], sa2 = asr[c0 + 2], sa3 = asr[c0 + 3];
    float da0 = ads[c0], da1 = ads[c0 + 1], da2 = ads[c0 + 2], da3 = ads[c0 + 3];
#pragma unroll
    for (int r = 0; r < 8; ++r) {
        int row = base + rg * 8 + r;
        if (row < NN) {
            ushort4 st;
            st.x = f2bu(acc[r].x); st.y = f2bu(acc[r].y);
            st.z = f2bu(acc[r].z); st.w = f2bu(acc[r].w);
            *(ushort4*)&h1[(size_t)row * 256 + c0] = st;
            float ps = acc[r].x * sa0 + acc[r].y * sa1 + acc[r].z * sa2 + acc[r].w * sa3;
            float pd = acc[r].x * da0 + acc[r].y * da1 + acc[r].z * da2 + acc[r].w * da3;
            ps += __shfl_xor(ps, 1, 64); ps += __shfl_xor(ps, 2, 64);
            pd += __shfl_xor(pd, 1, 64); pd += __shfl_xor(pd, 2, 64);
            if ((cg & 3) == 0) {
                a_src[row * 16 + h] = ps;
                a_dst[row * 16 + h] = pd;
            }
        }
    }
}

// ---------------- Layer 1 softmax stats: per (dst, head) m and 1/(l+eps) ----
__global__ void wpre1_k(const int* __restrict__ offs, const int* __restrict__ csr_src,
                        const float* __restrict__ a_src, const float* __restrict__ a_dst,
                        float2* __restrict__ ml1) {
    int gid = blockIdx.x * 256 + threadIdx.x;
    if (gid >= NN * 16) return;
    int dst = gid >> 4, h = gid & 15;
    int start = offs[dst], end = offs[dst + 1];
    float adst = a_dst[gid];
    float m = -INFINITY, l = 0.f;
    for (int j = start; j < end; ++j) {
        int s = csr_src[j];
        float e = a_src[s * 16 + h] + adst;
        e = (e > 0.f) ? e : 0.2f * e;
        float nm = fmaxf(m, e);
        l = l * __expf(m - nm) + __expf(e - nm);
        m = nm;
    }
    ml1[gid] = make_float2(m, 1.f / (l + 1e-16f));
}

// ---------------- Layer 1 aggregation: weighted gather-sum ------------------
// block 256 = one dst; tid = channel (head = tid>>4). No LDS, no barriers.
__global__ __launch_bounds__(256) void agg1_k(
    const int* __restrict__ offs, const int* __restrict__ csr_src,
    const float* __restrict__ a_src, const float* __restrict__ a_dst,
    const float2* __restrict__ ml1, const bf16* __restrict__ h1,
    const float* __restrict__ b1, bf16* __restrict__ out1) {
    int dst = blockIdx.x;
    int tid = threadIdx.x;
    int h = tid >> 4;
    int start = offs[dst], end = offs[dst + 1];
    float adst = a_dst[dst * 16 + h];
    float2 ml = ml1[dst * 16 + h];
    float acc = 0.f;
    int j = start;
    for (; j + 4 <= end; j += 4) {
        int s0 = csr_src[j], s1 = csr_src[j + 1], s2 = csr_src[j + 2], s3 = csr_src[j + 3];
        float as0 = a_src[s0 * 16 + h], as1 = a_src[s1 * 16 + h];
        float as2 = a_src[s2 * 16 + h], as3 = a_src[s3 * 16 + h];
        float hv0 = b2f(h1[(size_t)s0 * 256 + tid]);
        float hv1 = b2f(h1[(size_t)s1 * 256 + tid]);
        float hv2 = b2f(h1[(size_t)s2 * 256 + tid]);
        float hv3 = b2f(h1[(size_t)s3 * 256 + tid]);
        float e0 = as0 + adst; e0 = (e0 > 0.f) ? e0 : 0.2f * e0;
        float e1 = as1 + adst; e1 = (e1 > 0.f) ? e1 : 0.2f * e1;
        float e2 = as2 + adst; e2 = (e2 > 0.f) ? e2 : 0.2f * e2;
        float e3 = as3 + adst; e3 = (e3 > 0.f) ? e3 : 0.2f * e3;
        acc += __expf(e0 - ml.x) * ml.y * hv0;
        acc += __expf(e1 - ml.x) * ml.y * hv1;
        acc += __expf(e2 - ml.x) * ml.y * hv2;
        acc += __expf(e3 - ml.x) * ml.y * hv3;
    }
    for (; j < end; ++j) {
        int s = csr_src[j];
        float e = a_src[s * 16 + h] + adst;
        e = (e > 0.f) ? e : 0.2f * e;
        acc += __expf(e - ml.x) * ml.y * b2f(h1[(size_t)s * 256 + tid]);
    }
    out1[(size_t)dst * 256 + tid] = __float2bfloat16(acc + b1[tid]);
}

// ---------------- Layer 2 GEMM: h2 = out1@W2 (bf16 out) + alpha2 ------------
// block 256 = 64 rows x 64 cols; thread = 2 cols (cg*2) x 8 rows (rg*8..+7)
__global__ __launch_bounds__(256) void gemm2_k(
    const bf16* __restrict__ out1, const float* __restrict__ W2,
    const float* __restrict__ asr2, const float* __restrict__ ads2,
    bf16* __restrict__ h2, float* __restrict__ a_src2, float* __restrict__ a_dst2) {
    __shared__ bf16 ys[64 * 256];   // 32 KB
    int tid = threadIdx.x;
    int base = blockIdx.x * 64;
    uint4* ys16 = (uint4*)ys;
    const uint4* in16 = (const uint4*)out1;
    for (int i = tid; i < 2048; i += 256) {
        int row = base + (i >> 5);                 // 32 uint4 per row (256 bf16)
        uint4 z; z.x = z.y = z.z = z.w = 0u;
        ys16[i] = (row < NN) ? in16[(size_t)base * 32 + i] : z;
    }
    __syncthreads();
    int cg = tid & 31, rg = tid >> 5;
    int c0 = cg * 2;
    float2 acc[8];
#pragma unroll
    for (int r = 0; r < 8; ++r) acc[r] = make_float2(0.f, 0.f);
    for (int kq = 0; kq < 64; ++kq) {
        float2 w0 = *(const float2*)&W2[(kq * 4 + 0) * 64 + c0];
        float2 w1 = *(const float2*)&W2[(kq * 4 + 1) * 64 + c0];
        float2 w2 = *(const float2*)&W2[(kq * 4 + 2) * 64 + c0];
        float2 w3 = *(const float2*)&W2[(kq * 4 + 3) * 64 + c0];
#pragma unroll
        for (int r = 0; r < 8; ++r) {
            const __hip_bfloat162* yp =
                (const __hip_bfloat162*)&ys[(rg * 8 + r) * 256 + kq * 4];
            float2 y01 = __bfloat1622float2(yp[0]);
            float2 y23 = __bfloat1622float2(yp[1]);
            acc[r].x += y01.x * w0.x + y01.y * w1.x + y23.x * w2.x + y23.y * w3.x;
            acc[r].y += y01.x * w0.y + y01.y * w1.y + y23.x * w2.y + y23.y * w3.y;
        }
    }
    float sa0 = asr2[c0], sa1 = asr2[c0 + 1];
    float da0 = ads2[c0], da1 = ads2[c0 + 1];
#pragma unroll
    for (int r = 0; r < 8; ++r) {
        int row = base + rg * 8 + r;
        if (row < NN) {
            __hip_bfloat162 hb;
            hb.x = __float2bfloat16(acc[r].x);
            hb.y = __float2bfloat16(acc[r].y);
            *(__hip_bfloat162*)&h2[(size_t)row * 64 + c0] = hb;
            float ps = acc[r].x * sa0 + acc[r].y * sa1;
            float pd = acc[r].x * da0 + acc[r].y * da1;
#pragma unroll
            for (int o = 1; o <= 16; o <<= 1) {
                ps += __shfl_xor(ps, o, 64);
                pd += __shfl_xor(pd, o, 64);
            }
            if (cg == 0) { a_src2[row] = ps; a_dst2[row] = pd; }
        }
    }
}

// ---------------- Layer 2 softmax stats (1 head): thread = dst --------------
__global__ void wpre2_k(const int* __restrict__ offs, const int* __restrict__ csr_src,
                        const float* __restrict__ a_src2, const float* __restrict__ a_dst2,
                        float2* __restrict__ ml2) {
    int dst = blockIdx.x * 256 + threadIdx.x;
    if (dst >= NN) return;
    int start = offs[dst], end = offs[dst + 1];
    float adst = a_dst2[dst];
    float m = -INFINITY, l = 0.f;
    for (int j = start; j < end; ++j) {
        int s = csr_src[j];
        float e = a_src2[s] + adst;
        e = (e > 0.f) ? e : 0.2f * e;
        float nm = fmaxf(m, e);
        l = l * __expf(m - nm) + __expf(e - nm);
        m = nm;
    }
    ml2[dst] = make_float2(m, 1.f / (l + 1e-16f));
}

// ---------------- Layer 2 aggregation + sigmoid (f32 out) -------------------
// block 256 = 4 dst (one wave each); lane = channel (64)
__global__ __launch_bounds__(256) void agg2_k(
    const int* __restrict__ offs, const int* __restrict__ csr_src,
    const float* __restrict__ a_src2, const float* __restrict__ a_dst2,
    const float2* __restrict__ ml2, const bf16* __restrict__ h2,
    const float* __restrict__ b2, float* __restrict__ out) {
    int wv = threadIdx.x >> 6;
    int c = threadIdx.x & 63;
    int dst = blockIdx.x * 4 + wv;
    if (dst >= NN) return;
    int start = offs[dst], end = offs[dst + 1];
    float adst = a_dst2[dst];
    float2 ml = ml2[dst];
    float acc = 0.f;
    int j = start;
    for (; j + 4 <= end; j += 4) {
        int s0 = csr_src[j], s1 = csr_src[j + 1], s2 = csr_src[j + 2], s3 = csr_src[j + 3];
        float as0 = a_src2[s0], as1 = a_src2[s1], as2 = a_src2[s2], as3 = a_src2[s3];
        float hv0 = b2f(h2[(size_t)s0 * 64 + c]);
        float hv1 = b2f(h2[(size_t)s1 * 64 + c]);
        float hv2 = b2f(h2[(size_t)s2 * 64 + c]);
        float hv3 = b2f(h2[(size_t)s3 * 64 + c]);
        float e0 = as0 + adst; e0 = (e0 > 0.f) ? e0 : 0.2f * e0;
        float e1 = as1 + adst; e1 = (e1 > 0.f) ? e1 : 0.2f * e1;
        float e2 = as2 + adst; e2 = (e2 > 0.f) ? e2 : 0.2f * e2;
        float e3 = as3 + adst; e3 = (e3 > 0.f) ? e3 : 0.2f * e3;
        acc += __expf(e0 - ml.x) * ml.y * hv0;
        acc += __expf(e1 - ml.x) * ml.y * hv1;
        acc += __expf(e2 - ml.x) * ml.y * hv2;
        acc += __expf(e3 - ml.x) * ml.y * hv3;
    }
    for (; j < end; ++j) {
        int s = csr_src[j];
        float e = a_src2[s] + adst;
        e = (e > 0.f) ? e : 0.2f * e;
        acc += __expf(e - ml.x) * ml.y * b2f(h2[(size_t)s * 64 + c]);
    }
    float o = acc + b2[c];
    out[(size_t)dst * 64 + c] = 1.f / (1.f + __expf(-o));
}

// ---------------- host ------------------------------------------------------

extern "C" void kernel_launch(void* const* d_in, const int* in_sizes, int n_in,
                              void* d_out, int out_size, void* d_ws, size_t ws_size,
                              hipStream_t stream) {
    const float* x    = (const float*)d_in[0];
    const void*  ei   = d_in[1];
    const float* W1   = (const float*)d_in[2];
    const float* asr1 = (const float*)d_in[3];
    const float* ads1 = (const float*)d_in[4];
    const float* b1   = (const float*)d_in[5];
    const float* W2   = (const float*)d_in[6];
    const float* asr2 = (const float*)d_in[7];
    const float* ads2 = (const float*)d_in[8];
    const float* b2   = (const float*)d_in[9];
    float* out = (float*)d_out;

    char* w = (char*)d_ws;
    auto carve = [&](size_t bytes) {
        void* p = (void*)w;
        w += (bytes + 255) & ~(size_t)255;
        return p;
    };
    int*    flags    = (int*)carve(256);
    int*    csr_src  = (int*)carve((size_t)TE * 4);            // 3.4 MB
    int*    offs     = (int*)carve((size_t)(NN + 1) * 4);
    int*    deg      = (int*)carve((size_t)NN * 4);
    int*    cursor   = (int*)carve((size_t)NN * 4);
    int*    chunkoff = (int*)carve(256 * 4);
    float*  a_src1   = (float*)carve((size_t)NN * 16 * 4);     // 3.2 MB
    float*  a_dst1   = (float*)carve((size_t)NN * 16 * 4);     // 3.2 MB
    float2* ml1      = (float2*)carve((size_t)NN * 16 * 8);    // 6.4 MB
    bf16*   h1       = (bf16*)carve((size_t)NN * 256 * 2);     // 25.6 MB
    bf16*   out1     = (bf16*)carve((size_t)NN * 256 * 2);     // 25.6 MB
    // layer-2 buffers alias h1 (dead after agg1): 6.4+0.2+0.2+0.4 < 25.6 MB
    char*   l2base   = (char*)h1;
    bf16*   h2       = (bf16*)l2base;                          // 6.4 MB
    float*  a_src2   = (float*)(l2base + (size_t)NN * 64 * 2);
    float*  a_dst2   = a_src2 + NN;
    float2* ml2      = (float2*)(a_dst2 + NN);
    // peak carve ~68 MB

    hipMemsetAsync(deg, 0, (size_t)NN * 4, stream);
    hipMemsetAsync(cursor, 0, (size_t)NN * 4, stream);

    detect_k<<<1, 256, 0, stream>>>((const unsigned int*)ei, flags);

    const int egrid = (TE + 255) / 256;
    count_deg_k<<<egrid, 256, 0, stream>>>(ei, flags, deg);
    scan_chunks_k<<<1, 256, 0, stream>>>(deg, chunkoff);
    scan_within_k<<<NCH, 256, 0, stream>>>(deg, chunkoff, offs);
    fill_csr_k<<<egrid, 256, 0, stream>>>(ei, flags, offs, cursor, csr_src);

    gemm1_k<<<(NN + 31) / 32, 256, 0, stream>>>(x, W1, asr1, ads1, h1, a_src1, a_dst1);
    wpre1_k<<<(NN * 16 + 255) / 256, 256, 0, stream>>>(offs, csr_src, a_src1, a_dst1, ml1);
    agg1_k<<<NN, 256, 0, stream>>>(offs, csr_src, a_src1, a_dst1, ml1, h1, b1, out1);
    gemm2_k<<<(NN + 63) / 64, 256, 0, stream>>>(out1, W2, asr2, ads2, h2, a_src2, a_dst2);
    wpre2_k<<<(NN + 255) / 256, 256, 0, stream>>>(offs, csr_src, a_src2, a_dst2, ml2);
    agg2_k<<<(NN + 3) / 4, 256, 0, stream>>>(offs, csr_src, a_src2, a_dst2, ml2, h2, b2, out);
}